// Round 4
// baseline (675.045 us; speedup 1.0000x reference)
//
#include <hip/hip_runtime.h>
#include <cstdint>
#include <cstddef>

typedef __bf16 bf16_t;
typedef __bf16 bf16x8 __attribute__((ext_vector_type(8)));
typedef __bf16 bf16x4 __attribute__((ext_vector_type(4)));
typedef __bf16 bf16x2 __attribute__((ext_vector_type(2)));
typedef float  f32x4  __attribute__((ext_vector_type(4)));

typedef __attribute__((address_space(1))) void gvoid_t;
typedef __attribute__((address_space(3))) void lvoid_t;

__device__ __forceinline__ f32x4 mfma16(bf16x8 a, bf16x8 b, f32x4 c) {
  return __builtin_amdgcn_mfma_f32_16x16x32_bf16(a, b, c, 0, 0, 0);
}

__device__ __forceinline__ void async_copy16(const void* g, void* l) {
  __builtin_amdgcn_global_load_lds((gvoid_t*)g, (lvoid_t*)l, 16, 0, 0);
}

__device__ __forceinline__ float gelu_tanh(float x) {
  // jax.nn.gelu approximate=True
  float u = 0.7978845608028654f * (x + 0.044715f * x * x * x);
  float e = exp2f(2.8853900817779268f * u);   // e^{2u}
  float t = 1.f - 2.f / (e + 1.f);            // tanh(u)
  return 0.5f * x * (1.f + t);
}

// ---------- batched weight transpose: f32 [K,N] -> bf16 [N,K], 8 matrices, 1 launch ----------
struct TransBatch {
  const float* src[8];
  bf16_t* dst[8];
  int K[8], N[8], bx[8], base[8];  // base = starting linear tile id
};

__global__ void transpose_batch_kernel(TransBatch d) {
  int id = blockIdx.x;
  int mi = 0;
#pragma unroll
  for (int j = 1; j < 8; j++)
    if (id >= d.base[j]) mi = j;
  int local = id - d.base[mi];
  int bxw = d.bx[mi];
  int n0 = (local % bxw) * 32, k0 = (local / bxw) * 32;
  const float* in = d.src[mi];
  bf16_t* out = d.dst[mi];
  int K = d.K[mi], N = d.N[mi];

  __shared__ float t[32][33];
  int tx = threadIdx.x, ty = threadIdx.y;
#pragma unroll
  for (int i = 0; i < 4; i++)
    t[ty + i * 8][tx] = in[(size_t)(k0 + ty + i * 8) * N + n0 + tx];
  __syncthreads();
#pragma unroll
  for (int i = 0; i < 4; i++)
    out[(size_t)(n0 + ty + i * 8) * K + k0 + tx] = (bf16_t)t[tx][ty + i * 8];
}

// ---------- V transpose: vk bf16 [4][1024][1024] (cols 0..511) -> vt [4][512][1024] ----------
__global__ void transpose_v_kernel(const bf16_t* __restrict__ vk, bf16_t* __restrict__ vt) {
  __shared__ bf16_t t[32][33];
  int b = blockIdx.z;
  int d0 = blockIdx.x * 32, m0 = blockIdx.y * 32;
  int tx = threadIdx.x, ty = threadIdx.y;
#pragma unroll
  for (int i = 0; i < 4; i++)
    t[ty + i * 8][tx] = vk[((size_t)b * 1024 + m0 + ty + i * 8) * 1024 + d0 + tx];
  __syncthreads();
#pragma unroll
  for (int i = 0; i < 4; i++)
    vt[((size_t)b * 512 + d0 + ty + i * 8) * 1024 + m0 + tx] = t[tx][ty + i * 8];
}

// ---------- f32 -> bf16 convert, two tensors in one launch ----------
__global__ void cvt2_bf16_kernel(const float* __restrict__ a, bf16_t* __restrict__ oa, int n4a,
                                 const float* __restrict__ b, bf16_t* __restrict__ ob, int n4b) {
  int i = blockIdx.x * blockDim.x + threadIdx.x;
  const float* s;
  bf16_t* o;
  int j;
  if (i < n4a) { s = a; o = oa; j = i; }
  else { j = i - n4a; if (j >= n4b) return; s = b; o = ob; }
  float4 v = ((const float4*)s)[j];
  bf16x4 r = {(bf16_t)v.x, (bf16_t)v.y, (bf16_t)v.z, (bf16_t)v.w};
  ((bf16x4*)o)[j] = r;
}

// ---------- wave-per-row LN/RMS: vectorized loads, wave-local reduction ----------
template <int D, bool IS_RMS, typename TI>
__global__ __launch_bounds__(256) void rownorm_kernel(
    const TI* __restrict__ x, const float* __restrict__ g,
    const float* __restrict__ bb, bf16_t* __restrict__ out) {
  constexpr int V = D / 64;
  const int row = blockIdx.x * 4 + (threadIdx.x >> 6);
  const int lane = threadIdx.x & 63;
  const size_t base = (size_t)row * D + (size_t)lane * V;
  float v[V];
  if constexpr (sizeof(TI) == 2) {
    bf16x8 xv = *(const bf16x8*)(x + base);   // only used with V==8
#pragma unroll
    for (int j = 0; j < V; j++) v[j] = (float)xv[j];
  } else if constexpr (V == 8) {
    float4 a = ((const float4*)(x + base))[0];
    float4 b2 = ((const float4*)(x + base))[1];
    v[0] = a.x; v[1] = a.y; v[2] = a.z; v[3] = a.w;
    v[4] = b2.x; v[5] = b2.y; v[6] = b2.z; v[7] = b2.w;
  } else {
    float2 a = *(const float2*)(x + base);
    v[0] = a.x; v[1] = a.y;
  }
  float s = 0.f, s2 = 0.f;
#pragma unroll
  for (int j = 0; j < V; j++) { s += v[j]; s2 += v[j] * v[j]; }
#pragma unroll
  for (int o = 32; o > 0; o >>= 1) { s += __shfl_xor(s, o); s2 += __shfl_xor(s2, o); }
  float mu, rr;
  if constexpr (IS_RMS) {
    mu = 0.f;
    rr = rsqrtf(s2 * (1.f / D) + 1e-6f);
  } else {
    mu = s * (1.f / D);
    rr = rsqrtf(s2 * (1.f / D) - mu * mu + 1e-5f);
  }
  float o[V];
#pragma unroll
  for (int j = 0; j < V; j++) {
    float gv = g[lane * V + j];
    float bv;
    if constexpr (IS_RMS) bv = 0.f; else bv = bb[lane * V + j];
    o[j] = (v[j] - mu) * rr * gv + bv;
  }
  if constexpr (V == 8) {
    bf16x8 ov;
#pragma unroll
    for (int j = 0; j < 8; j++) ov[j] = (bf16_t)o[j];
    *(bf16x8*)(out + base) = ov;
  } else {
    bf16x2 ov;
    ov[0] = (bf16_t)o[0]; ov[1] = (bf16_t)o[1];
    *(bf16x2*)(out + base) = ov;
  }
}

// ---------- GEMM 128x128 tile, BK=64 (m97-class) ----------
template <int EPI>
__global__ __launch_bounds__(256, 2) void gemm_bt(
    const bf16_t* __restrict__ A, const bf16_t* __restrict__ Bt,
    const float* __restrict__ bias, void* __restrict__ outp,
    int M, int N, int K) {
  __shared__ __align__(16) bf16_t As[128 * 64];
  __shared__ __align__(16) bf16_t Bs[128 * 64];
  const int tid = threadIdx.x;
  const int lane = tid & 63, wv = tid >> 6;
  const int quad = lane >> 4, l16 = lane & 15;
  // bijective XCD swizzle (nwg % 8 == 0 for all our launches)
  int nwg = gridDim.x * gridDim.y;
  int bid = blockIdx.y * gridDim.x + blockIdx.x;
  if (!(nwg & 7)) { int cpx = nwg >> 3; bid = (bid & 7) * cpx + (bid >> 3); }
  const int m_base = (bid / gridDim.x) * 128, n_base = (bid % gridDim.x) * 128;
  const int wm = wv & 1, wn = wv >> 1;
  f32x4 acc[4][4] = {};

  for (int k0 = 0; k0 < K; k0 += 64) {
#pragma unroll
    for (int c = 0; c < 4; c++) {
      int p = c * 256 + tid;                 // 1024 chunks: 128 rows x 8 chunks of 8 bf16
      int row = p >> 3;
      int gc = (p & 7) ^ (row & 7);          // XOR swizzle
      async_copy16(&A[(size_t)(m_base + row) * K + k0 + gc * 8], &As[(size_t)p * 8]);
      async_copy16(&Bt[(size_t)(n_base + row) * K + k0 + gc * 8], &Bs[(size_t)p * 8]);
    }
    __syncthreads();
#pragma unroll
    for (int ks = 0; ks < 2; ks++) {
      bf16x8 af[4], bfr[4];
#pragma unroll
      for (int mi = 0; mi < 4; mi++) {
        int r = wm * 64 + mi * 16 + l16;
        int c = (ks * 4 + quad) ^ (r & 7);
        af[mi] = *(const bf16x8*)&As[(size_t)(r * 8 + c) * 8];
      }
#pragma unroll
      for (int ni = 0; ni < 4; ni++) {
        int r = wn * 64 + ni * 16 + l16;
        int c = (ks * 4 + quad) ^ (r & 7);
        bfr[ni] = *(const bf16x8*)&Bs[(size_t)(r * 8 + c) * 8];
      }
#pragma unroll
      for (int mi = 0; mi < 4; mi++)
#pragma unroll
        for (int ni = 0; ni < 4; ni++)
          acc[mi][ni] = mfma16(af[mi], bfr[ni], acc[mi][ni]);
    }
    __syncthreads();
  }

#pragma unroll
  for (int mi = 0; mi < 4; mi++) {
    int m = m_base + wm * 64 + mi * 16 + quad * 4;
#pragma unroll
    for (int ni = 0; ni < 4; ni++) {
      int n = n_base + wn * 64 + ni * 16 + l16;
      float bv = bias[n];
#pragma unroll
      for (int r2 = 0; r2 < 4; r2++) {
        float v = acc[mi][ni][r2] + bv;
        if (EPI == 2) v = gelu_tanh(v);
        if (EPI == 0) ((float*)outp)[(size_t)(m + r2) * N + n] = v;
        else          ((bf16_t*)outp)[(size_t)(m + r2) * N + n] = (bf16_t)v;
      }
    }
  }
}

// ---------- GEMM 256x256 tile, BK=64, 8-phase, read-ahead pipeline (v3) ----------
// Phase p: {issue reads for phase p+1 | issue stage | MFMA(p) on regs read at p-1 |
//           lgkmcnt(0) (free: reads drained under the MFMA burst) | [vmcnt(4)] | barrier}.
// Invariant: ALL ds_reads drained at every barrier -> cross-wave WAR on restaged slots safe.
// vmcnt(4) at ph3 confirms tile O (last half staged ph1) before ph4 pre-reads buf1;
// vmcnt(4) at ph7 confirms tile F (last half staged ph5) before ph8 pre-reads buf0.
// Fragment regs double-buffered (af0/af1, bf0/bf1): phase p reads into buf (p+1)&1,
// MFMA consumes buf p&1. ~248 VGPR at the 256 cap (2 waves/SIMD).
#define SF __builtin_amdgcn_sched_barrier(0)

template <int EPI>
__global__ __launch_bounds__(512, 2) void gemm256(
    const bf16_t* __restrict__ A, const bf16_t* __restrict__ Bt,
    const float* __restrict__ bias, void* __restrict__ outp,
    int M, int N, int K) {
  __shared__ __align__(16) bf16_t As[2][256 * 64];
  __shared__ __align__(16) bf16_t Bs[2][256 * 64];
  const int tid = threadIdx.x;
  const int lane = tid & 63, wid = tid >> 6;
  const int quad = lane >> 4, l16 = lane & 15, l7 = l16 & 7;
  const int wm = wid >> 2, wn = wid & 3;
  int nwg = gridDim.x * gridDim.y;
  int bid = blockIdx.y * gridDim.x + blockIdx.x;
  if (!(nwg & 7)) { int cpx = nwg >> 3; bid = (bid & 7) * cpx + (bid >> 3); }
  const int m_base = (bid / gridDim.x) * 256, n_base = (bid % gridDim.x) * 256;
  const int nit = K >> 7;   // 2 K-tiles per iteration

  f32x4 acc[8][4] = {};

  // per-thread LDS read bases; all other read addressing is compile-time immediates
  const bf16_t* aB[2]; const bf16_t* bB[2];
#pragma unroll
  for (int ks = 0; ks < 2; ks++) {
    aB[ks] = &As[0][0] + (wm * 128 + l16) * 64 + (((ks * 4 + quad) ^ l7)) * 8;
    bB[ks] = &Bs[0][0] + (wn * 64 + l16) * 64 + (((ks * 4 + quad) ^ l7)) * 8;
  }
  auto ldA = [&](int buf, int rg, bf16x8 (&af)[2][2]) {
#pragma unroll
    for (int mi = 0; mi < 2; mi++)
#pragma unroll
      for (int ks = 0; ks < 2; ks++)
        af[mi][ks] = *(const bf16x8*)(aB[ks] + buf * 16384 + rg * 2048 + mi * 1024);
  };
  auto ldB = [&](int buf, bf16x8 (&bfr)[4][2]) {
#pragma unroll
    for (int cf = 0; cf < 4; cf++)
#pragma unroll
      for (int ks = 0; ks < 2; ks++)
        bfr[cf][ks] = *(const bf16x8*)(bB[ks] + buf * 16384 + cf * 1024);
  };
  auto mm = [&](int rg, bf16x8 (&a)[2][2], bf16x8 (&b)[4][2]) {
#pragma unroll
    for (int ks = 0; ks < 2; ks++)
#pragma unroll
      for (int mi = 0; mi < 2; mi++)
#pragma unroll
        for (int cf = 0; cf < 4; cf++)
          acc[rg * 2 + mi][cf] = mfma16(a[mi][ks], b[cf][ks], acc[rg * 2 + mi][cf]);
  };

  // per-thread global stage streams, +128 B per stage event (K-tile order).
  // Streams run <=2 events past nkt (tail prefetch garbage): reads <=4 KB past the
  // buffer end; all staged sources here are followed by another workspace buffer.
  const int rr = tid >> 3;
  const int cb = ((tid & 7) ^ (rr & 7)) * 16;
  const char* pa00 = (const char*)A + 2 * ((size_t)(m_base + 0 + rr) * K) + cb;
  const char* pa01 = (const char*)A + 2 * ((size_t)(m_base + 64 + rr) * K) + cb;
  const char* pa10 = (const char*)A + 2 * ((size_t)(m_base + 128 + rr) * K) + cb;
  const char* pa11 = (const char*)A + 2 * ((size_t)(m_base + 192 + rr) * K) + cb;
  const char* pb00 = (const char*)Bt + 2 * ((size_t)(n_base + 0 + rr) * K) + cb;
  const char* pb01 = (const char*)Bt + 2 * ((size_t)(n_base + 64 + rr) * K) + cb;
  const char* pb10 = (const char*)Bt + 2 * ((size_t)(n_base + 128 + rr) * K) + cb;
  const char* pb11 = (const char*)Bt + 2 * ((size_t)(n_base + 192 + rr) * K) + cb;
  bf16_t* dA0 = &As[0][0] + tid * 8;
  bf16_t* dB0 = &Bs[0][0] + tid * 8;
  auto stage = [&](const char*& p0, const char*& p1, bf16_t* d0) {
    async_copy16(p0, d0);
    async_copy16(p1, d0 + 4096);
    p0 += 128; p1 += 128;
  };

  // ---- prologue: E (kt0) fully + O (kt1) {Bh0,Bh1,Ah0}; vmcnt(6) confirms E ----
  stage(pb00, pb01, dB0);
  stage(pb10, pb11, dB0 + 8192);
  stage(pa00, pa01, dA0);
  stage(pa10, pa11, dA0 + 8192);
  stage(pb00, pb01, dB0 + 16384);
  stage(pb10, pb11, dB0 + 16384 + 8192);
  stage(pa00, pa01, dA0 + 16384);
  asm volatile("s_waitcnt vmcnt(6)" ::: "memory");
  SF; __builtin_amdgcn_s_barrier(); SF;

  bf16x8 af0[2][2], af1[2][2], bf0[4][2], bf1[4][2];
  ldB(0, bf0); ldA(0, 0, af0);   // frags for ph1 (drain at ph1's lgkmcnt(0))

  for (int it = 0; it < nit; ++it) {
    // ph1: MM rg0(E)[af0,bf0] | read rg1->af1 | stage O.Ah1
    ldA(0, 1, af1);
    stage(pa10, pa11, dA0 + 16384 + 8192);
    __builtin_amdgcn_s_setprio(1); mm(0, af0, bf0); __builtin_amdgcn_s_setprio(0);
    SF; asm volatile("s_waitcnt lgkmcnt(0)" ::: "memory");
    __builtin_amdgcn_s_barrier(); SF;
    // ph2: MM rg1[af1,bf0] | read rg2->af0 | stage F.Bh0
    ldA(0, 2, af0);
    stage(pb00, pb01, dB0);
    __builtin_amdgcn_s_setprio(1); mm(1, af1, bf0); __builtin_amdgcn_s_setprio(0);
    SF; asm volatile("s_waitcnt lgkmcnt(0)" ::: "memory");
    __builtin_amdgcn_s_barrier(); SF;
    // ph3: MM rg2[af0,bf0] | read rg3->af1 | stage F.Bh1 | vmcnt(4): O published
    ldA(0, 3, af1);
    stage(pb10, pb11, dB0 + 8192);
    __builtin_amdgcn_s_setprio(1); mm(2, af0, bf0); __builtin_amdgcn_s_setprio(0);
    SF; asm volatile("s_waitcnt vmcnt(4) lgkmcnt(0)" ::: "memory");
    __builtin_amdgcn_s_barrier(); SF;
    // ph4: MM rg3[af1,bf0] | read B(O)->bf1, A(O,rg0)->af0 | stage F.Ah0
    ldB(1, bf1); ldA(1, 0, af0);
    stage(pa00, pa01, dA0);
    __builtin_amdgcn_s_setprio(1); mm(3, af1, bf0); __builtin_amdgcn_s_setprio(0);
    SF; asm volatile("s_waitcnt lgkmcnt(0)" ::: "memory");
    __builtin_amdgcn_s_barrier(); SF;
    // ph5: MM rg0(O)[af0,bf1] | read rg1->af1 | stage F.Ah1
    ldA(1, 1, af1);
    stage(pa10, pa11, dA0 + 8192);
    __builtin_amdgcn_s_setprio(1); mm(0, af0, bf1); __builtin_amdgcn_s_setprio(0);
    SF; asm volatile("s_waitcnt lgkmcnt(0)" ::: "memory");
    __builtin_amdgcn_s_barrier(); SF;
    // ph6: MM rg1[af1,bf1] | read rg2->af0 | stage G.Bh0
    ldA(1, 2, af0);
    stage(pb00, pb01, dB0 + 16384);
    __builtin_amdgcn_s_setprio(1); mm(1, af1, bf1); __builtin_amdgcn_s_setprio(0);
    SF; asm volatile("s_waitcnt lgkmcnt(0)" ::: "memory");
    __builtin_amdgcn_s_barrier(); SF;
    // ph7: MM rg2[af0,bf1] | read rg3->af1 | stage G.Bh1 | vmcnt(4): F published
    ldA(1, 3, af1);
    stage(pb10, pb11, dB0 + 16384 + 8192);
    __builtin_amdgcn_s_setprio(1); mm(2, af0, bf1); __builtin_amdgcn_s_setprio(0);
    SF; asm volatile("s_waitcnt vmcnt(4) lgkmcnt(0)" ::: "memory");
    __builtin_amdgcn_s_barrier(); SF;
    // ph8: MM rg3[af1,bf1] | read B(F)->bf0, A(F,rg0)->af0 | stage G.Ah0
    ldB(0, bf0); ldA(0, 0, af0);
    stage(pa00, pa01, dA0 + 16384);
    __builtin_amdgcn_s_setprio(1); mm(3, af1, bf1); __builtin_amdgcn_s_setprio(0);
    SF; asm volatile("s_waitcnt lgkmcnt(0)" ::: "memory");
    __builtin_amdgcn_s_barrier(); SF;
  }
  asm volatile("s_waitcnt vmcnt(0)" ::: "memory");  // drain tail prefetches

#pragma unroll
  for (int rf = 0; rf < 8; rf++) {
    int m = m_base + wm * 128 + rf * 16 + quad * 4;
#pragma unroll
    for (int cf = 0; cf < 4; cf++) {
      int n = n_base + wn * 64 + cf * 16 + l16;
      float bv = bias[n];
#pragma unroll
      for (int r2 = 0; r2 < 4; r2++) {
        float v = acc[rf][cf][r2] + bv;
        if (EPI == 2) v = gelu_tanh(v);
        if (EPI == 0) ((float*)outp)[(size_t)(m + r2) * N + n] = v;
        else          ((bf16_t*)outp)[(size_t)(m + r2) * N + n] = (bf16_t)v;
      }
    }
  }
}

// ---------- GEMM 64x128 tile for small-K tail GEMMs ----------
template <int EPI>
__global__ __launch_bounds__(256, 2) void gemm64(
    const bf16_t* __restrict__ A, const bf16_t* __restrict__ Bt,
    const float* __restrict__ bias, void* __restrict__ outp,
    int M, int N, int K) {
  __shared__ __align__(16) bf16_t As[64 * 32];
  __shared__ __align__(16) bf16_t Bs[128 * 32];
  const int tid = threadIdx.x;
  const int lane = tid & 63, wv = tid >> 6;
  const int quad = lane >> 4, l16 = lane & 15;
  const int m_base = blockIdx.y * 64, n_base = blockIdx.x * 128;
  const int wm = wv & 1, wn = wv >> 1;
  f32x4 acc[2][4] = {};

  for (int k0 = 0; k0 < K; k0 += 32) {
    {
      int p = tid;                           // A: 64 rows x 4 chunks = 256
      int row = p >> 2;
      int kc = (p & 3) ^ ((row >> 1) & 3);
      async_copy16(&A[(size_t)(m_base + row) * K + k0 + kc * 8], &As[(size_t)p * 8]);
    }
#pragma unroll
    for (int c = 0; c < 2; c++) {
      int p = c * 256 + tid;                 // B: 128 rows x 4 chunks = 512
      int row = p >> 2;
      int kc = (p & 3) ^ ((row >> 1) & 3);
      async_copy16(&Bt[(size_t)(n_base + row) * K + k0 + kc * 8], &Bs[(size_t)p * 8]);
    }
    __syncthreads();
    bf16x8 af[2], bfr[4];
#pragma unroll
    for (int mi = 0; mi < 2; mi++) {
      int r = wm * 32 + mi * 16 + l16;
      int kc = quad ^ ((r >> 1) & 3);
      af[mi] = *(const bf16x8*)&As[(size_t)(r * 4 + kc) * 8];
    }
#pragma unroll
    for (int ni = 0; ni < 4; ni++) {
      int r = wn * 64 + ni * 16 + l16;
      int kc = quad ^ ((r >> 1) & 3);
      bfr[ni] = *(const bf16x8*)&Bs[(size_t)(r * 4 + kc) * 8];
    }
#pragma unroll
    for (int mi = 0; mi < 2; mi++)
#pragma unroll
      for (int ni = 0; ni < 4; ni++)
        acc[mi][ni] = mfma16(af[mi], bfr[ni], acc[mi][ni]);
    __syncthreads();
  }

#pragma unroll
  for (int mi = 0; mi < 2; mi++) {
    int m = m_base + wm * 32 + mi * 16 + quad * 4;
#pragma unroll
    for (int ni = 0; ni < 4; ni++) {
      int n = n_base + wn * 64 + ni * 16 + l16;
      float bv = bias[n];
#pragma unroll
      for (int r2 = 0; r2 < 4; r2++) {
        float v = acc[mi][ni][r2] + bv;
        if (EPI == 2) v = gelu_tanh(v);
        if (EPI == 0) ((float*)outp)[(size_t)(m + r2) * N + n] = v;
        else          ((bf16_t*)outp)[(size_t)(m + r2) * N + n] = (bf16_t)v;
      }
    }
  }
}

// ---------- fused dual-score attention, m97-style block-cooperative structure ----------
__global__ __launch_bounds__(256, 2) void attn_kernel(
    const bf16_t* __restrict__ qc, const bf16_t* __restrict__ qv,
    const bf16_t* __restrict__ kcb, const bf16_t* __restrict__ vkb,
    const bf16_t* __restrict__ vt, const float* __restrict__ lamp,
    bf16_t* __restrict__ vout) {
  const int b = blockIdx.z, h = blockIdx.y;
  const int tid = threadIdx.x;
  const int lane = tid & 63, wv = tid >> 6;
  const int quad = lane >> 4, l16 = lane & 15;
  const int qrow0 = blockIdx.x * 128 + wv * 32;
  const float SCL = 0.125f * 1.4426950408889634f;  // 1/sqrt(64) * log2(e)
  const float C1 = SCL, C2 = lamp[0] * SCL;

  __shared__ __align__(16) bf16_t kcS[64 * 64];
  __shared__ __align__(16) bf16_t kvS[64 * 64];
  __shared__ __align__(16) bf16_t vtS[64 * 64];
  __shared__ __align__(16) bf16_t sP[4][32 * 64];
  bf16_t* sPw = sP[wv];

  // Q fragments: A[m=q (l16)][k=d (ks*32+quad*8+j)]
  bf16x8 qcf[2][2], qvf[2][2];
#pragma unroll
  for (int mt = 0; mt < 2; mt++)
#pragma unroll
    for (int ks = 0; ks < 2; ks++) {
      size_t o = ((size_t)b * 4096 + qrow0 + mt * 16 + l16) * 512 + h * 64 + ks * 32 + quad * 8;
      qcf[mt][ks] = *(const bf16x8*)&qc[o];
      qvf[mt][ks] = *(const bf16x8*)&qv[o];
    }

  f32x4 O[2][4] = {};
  float ls[2][4] = {};

  for (int kb = 0; kb < 16; kb++) {
    // ---- stage kc/kv/vt 64x64 tiles (8 KB each): source-side XOR swizzle ----
#pragma unroll
    for (int i = 0; i < 2; i++) {
      int p = i * 256 + tid;            // 512 chunks of 16B per tile
      int row = p >> 3;                 // key row (kc/kv) or d row (vt)
      int gc = (p & 7) ^ (row & 7);     // global chunk for this LDS slot
      async_copy16(&kcb[((size_t)b * 1024 + kb * 64 + row) * 512 + h * 64 + gc * 8],
                   &kcS[(size_t)p * 8]);
      async_copy16(&vkb[((size_t)b * 1024 + kb * 64 + row) * 1024 + 512 + h * 64 + gc * 8],
                   &kvS[(size_t)p * 8]);
      async_copy16(&vt[((size_t)((b * 8 + h) * 64) + row) * 1024 + kb * 64 + gc * 8],
                   &vtS[(size_t)p * 8]);
    }
    __syncthreads();

    // ---- QK^T + exp -> per-wave P ----
#pragma unroll
    for (int nt = 0; nt < 4; nt++) {
      int krow = nt * 16 + l16;
      int kb8 = krow & 7;
      bf16x8 kc0 = *(const bf16x8*)&kcS[(size_t)(krow * 8 + (quad ^ kb8)) * 8];
      bf16x8 kc1 = *(const bf16x8*)&kcS[(size_t)(krow * 8 + ((4 + quad) ^ kb8)) * 8];
      bf16x8 kv0 = *(const bf16x8*)&kvS[(size_t)(krow * 8 + (quad ^ kb8)) * 8];
      bf16x8 kv1 = *(const bf16x8*)&kvS[(size_t)(krow * 8 + ((4 + quad) ^ kb8)) * 8];
#pragma unroll
      for (int mt = 0; mt < 2; mt++) {
        f32x4 sc = {};
        sc = mfma16(qcf[mt][0], kc0, sc);
        sc = mfma16(qcf[mt][1], kc1, sc);
        f32x4 sv = {};
        sv = mfma16(qvf[mt][0], kv0, sv);
        sv = mfma16(qvf[mt][1], kv1, sv);
#pragma unroll
        for (int r = 0; r < 4; r++) {
          float p = exp2f(sc[r] * C1 + sv[r] * C2);
          ls[mt][r] += p;
          int prow = mt * 16 + quad * 4 + r;
          int col = nt * 16 + l16;
          sPw[prow * 64 + (((col >> 3) ^ (prow & 7)) * 8) + (col & 7)] = (bf16_t)p;
        }
      }
    }
    // RAW: this wave's P writes must land before its reads (per-wave buffer)
    asm volatile("s_waitcnt lgkmcnt(0)" ::: "memory");

    // ---- PV: O[mt] += P[mt] @ V ----
#pragma unroll
    for (int ks2 = 0; ks2 < 2; ks2++) {
      bf16x8 pa[2];
#pragma unroll
      for (int mt = 0; mt < 2; mt++) {
        int prow = mt * 16 + l16;
        pa[mt] = *(const bf16x8*)&sPw[(size_t)(prow * 8 + ((ks2 * 4 + quad) ^ (prow & 7))) * 8];
      }
#pragma unroll
      for (int ntd = 0; ntd < 4; ntd++) {
        int drow = ntd * 16 + l16;
        bf16x8 vb = *(const bf16x8*)&vtS[(size_t)(drow * 8 + ((ks2 * 4 + quad) ^ (drow & 7))) * 8];
        O[0][ntd] = mfma16(pa[0], vb, O[0][ntd]);
        O[1][ntd] = mfma16(pa[1], vb, O[1][ntd]);
      }
    }
    __syncthreads();  // protect kc/kv/vt tiles before next stage (also WAR for sPw)
  }

  // ---- epilogue: denominator + write ----
#pragma unroll
  for (int mt = 0; mt < 2; mt++) {
    float inv[4];
#pragma unroll
    for (int r = 0; r < 4; r++) {
      float v = ls[mt][r];
      v += __shfl_xor(v, 1);
      v += __shfl_xor(v, 2);
      v += __shfl_xor(v, 4);
      v += __shfl_xor(v, 8);
      inv[r] = 1.f / v;
    }
#pragma unroll
    for (int ntd = 0; ntd < 4; ntd++)
#pragma unroll
      for (int r = 0; r < 4; r++) {
        size_t o = ((size_t)b * 4096 + qrow0 + mt * 16 + quad * 4 + r) * 512 + h * 64 + ntd * 16 + l16;
        vout[o] = (bf16_t)(O[mt][ntd][r] * inv[r]);
      }
  }
}

extern "C" void kernel_launch(void* const* d_in, const int* in_sizes, int n_in,
                              void* d_out, int out_size, void* d_ws, size_t ws_size,
                              hipStream_t stream) {
  (void)in_sizes; (void)n_in; (void)out_size; (void)ws_size;
  const float* coords = (const float*)d_in[0];
  const float* values = (const float*)d_in[1];
  const float* Lv     = (const float*)d_in[2];
  const float* Lc     = (const float*)d_in[3];
  const float* lam    = (const float*)d_in[4];
  const float* lvn_g  = (const float*)d_in[5];
  const float* lvn_b  = (const float*)d_in[6];
  const float* lcn_g  = (const float*)d_in[7];
  const float* lcn_b  = (const float*)d_in[8];
  const float* ck_w = (const float*)d_in[9];  const float* ck_b = (const float*)d_in[10]; const float* ck_g = (const float*)d_in[11];
  const float* cq_w = (const float*)d_in[12]; const float* cq_b = (const float*)d_in[13]; const float* cq_g = (const float*)d_in[14];
  const float* vq_w = (const float*)d_in[15]; const float* vq_b = (const float*)d_in[16]; const float* vq_g = (const float*)d_in[17];
  const float* vk_w = (const float*)d_in[18]; const float* vk_b = (const float*)d_in[19];
  const float* op_w = (const float*)d_in[20]; const float* op_b = (const float*)d_in[21];
  const float* oln_g = (const float*)d_in[22]; const float* oln_b = (const float*)d_in[23];
  const float* m1_w = (const float*)d_in[24]; const float* m1_b = (const float*)d_in[25];
  const float* m2_w = (const float*)d_in[26]; const float* m2_b = (const float*)d_in[27];
  const float* m3_w = (const float*)d_in[28]; const float* m3_b = (const float*)d_in[29];

  char* ws = (char*)d_ws;
  size_t off = 0;
  auto alloc = [&](size_t bytes) { void* p = ws + off; off += (bytes + 255) & ~(size_t)255; return p; };

  // persistent region
  bf16_t* wt_m1 = (bf16_t*)alloc((size_t)512 * 2048 * 2);
  bf16_t* wt_m2 = (bf16_t*)alloc((size_t)2048 * 2048 * 2);
  bf16_t* wt_m3 = (bf16_t*)alloc((size_t)2048 * 512 * 2);
  bf16_t* scr0  = (bf16_t*)alloc((size_t)16384 * 512 * 4);   // bf16 used, f32-sized slot kept
  bf16_t* qv_bf = (bf16_t*)alloc((size_t)16384 * 512 * 2);
  bf16_t* qc_bf = (bf16_t*)alloc((size_t)16384 * 512 * 2);
  bf16_t* voutb = (bf16_t*)alloc((size_t)16384 * 512 * 2);
  bf16_t* h0    = (bf16_t*)alloc((size_t)16384 * 512 * 2);
  bf16_t* h1    = (bf16_t*)alloc((size_t)16384 * 2048 * 2);
  bf16_t* h2    = (bf16_t*)alloc((size_t)16384 * 2048 * 2);

  // overlay region: everything here is dead before h1 is written (m1 GEMM)
  size_t ov = (size_t)((char*)h1 - ws);
  auto oalloc = [&](size_t bytes) { void* p = ws + ov; ov += (bytes + 255) & ~(size_t)255; return p; };
  bf16_t* wt_vk = (bf16_t*)oalloc((size_t)1024 * 512 * 2);
  bf16_t* wt_ck = (bf16_t*)oalloc((size_t)512 * 128 * 2);
  bf16_t* wt_cq = (bf16_t*)oalloc((size_t)512 * 128 * 2);
  bf16_t* wt_vq = (bf16_t*)oalloc((size_t)512 * 512 * 2);
  bf16_t* wt_op = (bf16_t*)oalloc((size_t)512 * 512 * 2);
  bf16_t* lv_ln = (bf16_t*)oalloc((size_t)4096 * 512 * 2);
  bf16_t* lc_ln = (bf16_t*)oalloc((size_t)4096 * 128 * 2);
  bf16_t* vkob  = (bf16_t*)oalloc((size_t)4096 * 1024 * 2);
  bf16_t* kc_b  = (bf16_t*)oalloc((size_t)4096 * 512 * 2);
  bf16_t* kc_bf = (bf16_t*)oalloc((size_t)4096 * 512 * 2);
  bf16_t* val_bf= (bf16_t*)oalloc((size_t)16384 * 512 * 2);
  bf16_t* crd_bf= (bf16_t*)oalloc((size_t)16384 * 128 * 2);
  bf16_t* vt    = (bf16_t*)oalloc((size_t)4 * 512 * 1024 * 2);

  // ---- single batched transpose launch for all 8 weights ----
  TransBatch tb8;
  const float* srcs[8] = {vk_w, ck_w, cq_w, vq_w, op_w, m1_w, m2_w, m3_w};
  bf16_t* dsts[8] = {wt_vk, wt_ck, wt_cq, wt_vq, wt_op, wt_m1, wt_m2, wt_m3};
  int Ks[8] = {512, 128, 128, 512, 512, 512, 2048, 2048};
  int Ns[8] = {1024, 512, 512, 512, 512, 2048, 2048, 512};
  int cum = 0;
  for (int i = 0; i < 8; i++) {
    tb8.src[i] = srcs[i]; tb8.dst[i] = dsts[i];
    tb8.K[i] = Ks[i]; tb8.N[i] = Ns[i];
    tb8.bx[i] = Ns[i] / 32;
    tb8.base[i] = cum;
    cum += (Ns[i] / 32) * (Ks[i] / 32);
  }
  transpose_batch_kernel<<<cum, dim3(32, 8), 0, stream>>>(tb8);

  cvt2_bf16_kernel<<<(16384 * 512 / 4 + 16384 * 128 / 4 + 255) / 256, 256, 0, stream>>>(
      values, val_bf, 16384 * 512 / 4, coords, crd_bf, 16384 * 128 / 4);

  rownorm_kernel<512, false, float><<<1024, 256, 0, stream>>>(Lv, lvn_g, lvn_b, lv_ln);
  rownorm_kernel<128, false, float><<<1024, 256, 0, stream>>>(Lc, lcn_g, lcn_b, lc_ln);

  gemm_bt<1><<<dim3(8, 32), 256, 0, stream>>>(lv_ln, wt_vk, vk_b, vkob, 4096, 1024, 512);
  gemm64<1><<<dim3(4, 64), 256, 0, stream>>>(lc_ln, wt_ck, ck_b, kc_b, 4096, 512, 128);
  rownorm_kernel<512, true, bf16_t><<<1024, 256, 0, stream>>>(kc_b, ck_g, nullptr, kc_bf);

  gemm_bt<1><<<dim3(4, 128), 256, 0, stream>>>(val_bf, wt_vq, vq_b, scr0, 16384, 512, 512);
  rownorm_kernel<512, true, bf16_t><<<4096, 256, 0, stream>>>(scr0, vq_g, nullptr, qv_bf);
  gemm64<1><<<dim3(4, 256), 256, 0, stream>>>(crd_bf, wt_cq, cq_b, scr0, 16384, 512, 128);
  rownorm_kernel<512, true, bf16_t><<<4096, 256, 0, stream>>>(scr0, cq_g, nullptr, qc_bf);

  transpose_v_kernel<<<dim3(16, 32, 4), dim3(32, 8), 0, stream>>>(vkob, vt);

  attn_kernel<<<dim3(32, 8, 4), 256, 0, stream>>>(qc_bf, qv_bf, kc_bf, vkob, vt, lam, voutb);

  gemm_bt<1><<<dim3(4, 128), 256, 0, stream>>>(voutb, wt_op, op_b, scr0, 16384, 512, 512);
  rownorm_kernel<512, false, bf16_t><<<4096, 256, 0, stream>>>(scr0, oln_g, oln_b, h0);

  gemm256<2><<<dim3(8, 64), 512, 0, stream>>>(h0, wt_m1, m1_b, h1, 16384, 2048, 512);
  gemm256<2><<<dim3(8, 64), 512, 0, stream>>>(h1, wt_m2, m2_b, h2, 16384, 2048, 2048);
  gemm_bt<0><<<dim3(4, 128), 256, 0, stream>>>(h2, wt_m3, m3_b, (float*)d_out, 16384, 512, 2048);
}

// Round 5
// 582.839 us; speedup vs baseline: 1.1582x; 1.1582x over previous
//
#include <hip/hip_runtime.h>
#include <cstdint>
#include <cstddef>

typedef __bf16 bf16_t;
typedef __bf16 bf16x8 __attribute__((ext_vector_type(8)));
typedef __bf16 bf16x4 __attribute__((ext_vector_type(4)));
typedef __bf16 bf16x2 __attribute__((ext_vector_type(2)));
typedef float  f32x4  __attribute__((ext_vector_type(4)));

typedef __attribute__((address_space(1))) void gvoid_t;
typedef __attribute__((address_space(3))) void lvoid_t;

__device__ __forceinline__ f32x4 mfma16(bf16x8 a, bf16x8 b, f32x4 c) {
  return __builtin_amdgcn_mfma_f32_16x16x32_bf16(a, b, c, 0, 0, 0);
}

__device__ __forceinline__ void async_copy16(const void* g, void* l) {
  __builtin_amdgcn_global_load_lds((gvoid_t*)g, (lvoid_t*)l, 16, 0, 0);
}

__device__ __forceinline__ float gelu_tanh(float x) {
  // jax.nn.gelu approximate=True
  float u = 0.7978845608028654f * (x + 0.044715f * x * x * x);
  float e = exp2f(2.8853900817779268f * u);   // e^{2u}
  float t = 1.f - 2.f / (e + 1.f);            // tanh(u)
  return 0.5f * x * (1.f + t);
}

// ---------- batched weight transpose: f32 [K,N] -> bf16 [N,K], 8 matrices, 1 launch ----------
struct TransBatch {
  const float* src[8];
  bf16_t* dst[8];
  int K[8], N[8], bx[8], base[8];  // base = starting linear tile id
};

__global__ void transpose_batch_kernel(TransBatch d) {
  int id = blockIdx.x;
  int mi = 0;
#pragma unroll
  for (int j = 1; j < 8; j++)
    if (id >= d.base[j]) mi = j;
  int local = id - d.base[mi];
  int bxw = d.bx[mi];
  int n0 = (local % bxw) * 32, k0 = (local / bxw) * 32;
  const float* in = d.src[mi];
  bf16_t* out = d.dst[mi];
  int K = d.K[mi], N = d.N[mi];

  __shared__ float t[32][33];
  int tx = threadIdx.x, ty = threadIdx.y;
#pragma unroll
  for (int i = 0; i < 4; i++)
    t[ty + i * 8][tx] = in[(size_t)(k0 + ty + i * 8) * N + n0 + tx];
  __syncthreads();
#pragma unroll
  for (int i = 0; i < 4; i++)
    out[(size_t)(n0 + ty + i * 8) * K + k0 + tx] = (bf16_t)t[tx][ty + i * 8];
}

// ---------- V transpose: vk bf16 [4][1024][1024] (cols 0..511) -> vt [4][512][1024] ----------
__global__ void transpose_v_kernel(const bf16_t* __restrict__ vk, bf16_t* __restrict__ vt) {
  __shared__ bf16_t t[32][33];
  int b = blockIdx.z;
  int d0 = blockIdx.x * 32, m0 = blockIdx.y * 32;
  int tx = threadIdx.x, ty = threadIdx.y;
#pragma unroll
  for (int i = 0; i < 4; i++)
    t[ty + i * 8][tx] = vk[((size_t)b * 1024 + m0 + ty + i * 8) * 1024 + d0 + tx];
  __syncthreads();
#pragma unroll
  for (int i = 0; i < 4; i++)
    vt[((size_t)b * 512 + d0 + ty + i * 8) * 1024 + m0 + tx] = t[tx][ty + i * 8];
}

// ---------- f32 -> bf16 convert, two tensors in one launch ----------
__global__ void cvt2_bf16_kernel(const float* __restrict__ a, bf16_t* __restrict__ oa, int n4a,
                                 const float* __restrict__ b, bf16_t* __restrict__ ob, int n4b) {
  int i = blockIdx.x * blockDim.x + threadIdx.x;
  const float* s;
  bf16_t* o;
  int j;
  if (i < n4a) { s = a; o = oa; j = i; }
  else { j = i - n4a; if (j >= n4b) return; s = b; o = ob; }
  float4 v = ((const float4*)s)[j];
  bf16x4 r = {(bf16_t)v.x, (bf16_t)v.y, (bf16_t)v.z, (bf16_t)v.w};
  ((bf16x4*)o)[j] = r;
}

// ---------- wave-per-row LN/RMS: vectorized loads, wave-local reduction ----------
template <int D, bool IS_RMS, typename TI>
__global__ __launch_bounds__(256) void rownorm_kernel(
    const TI* __restrict__ x, const float* __restrict__ g,
    const float* __restrict__ bb, bf16_t* __restrict__ out) {
  constexpr int V = D / 64;
  const int row = blockIdx.x * 4 + (threadIdx.x >> 6);
  const int lane = threadIdx.x & 63;
  const size_t base = (size_t)row * D + (size_t)lane * V;
  float v[V];
  if constexpr (sizeof(TI) == 2) {
    bf16x8 xv = *(const bf16x8*)(x + base);   // only used with V==8
#pragma unroll
    for (int j = 0; j < V; j++) v[j] = (float)xv[j];
  } else if constexpr (V == 8) {
    float4 a = ((const float4*)(x + base))[0];
    float4 b2 = ((const float4*)(x + base))[1];
    v[0] = a.x; v[1] = a.y; v[2] = a.z; v[3] = a.w;
    v[4] = b2.x; v[5] = b2.y; v[6] = b2.z; v[7] = b2.w;
  } else {
    float2 a = *(const float2*)(x + base);
    v[0] = a.x; v[1] = a.y;
  }
  float s = 0.f, s2 = 0.f;
#pragma unroll
  for (int j = 0; j < V; j++) { s += v[j]; s2 += v[j] * v[j]; }
#pragma unroll
  for (int o = 32; o > 0; o >>= 1) { s += __shfl_xor(s, o); s2 += __shfl_xor(s2, o); }
  float mu, rr;
  if constexpr (IS_RMS) {
    mu = 0.f;
    rr = rsqrtf(s2 * (1.f / D) + 1e-6f);
  } else {
    mu = s * (1.f / D);
    rr = rsqrtf(s2 * (1.f / D) - mu * mu + 1e-5f);
  }
  float o[V];
#pragma unroll
  for (int j = 0; j < V; j++) {
    float gv = g[lane * V + j];
    float bv;
    if constexpr (IS_RMS) bv = 0.f; else bv = bb[lane * V + j];
    o[j] = (v[j] - mu) * rr * gv + bv;
  }
  if constexpr (V == 8) {
    bf16x8 ov;
#pragma unroll
    for (int j = 0; j < 8; j++) ov[j] = (bf16_t)o[j];
    *(bf16x8*)(out + base) = ov;
  } else {
    bf16x2 ov;
    ov[0] = (bf16_t)o[0]; ov[1] = (bf16_t)o[1];
    *(bf16x2*)(out + base) = ov;
  }
}

// ---------- GEMM 128x128 tile, BK=64 (m97-class) ----------
template <int EPI>
__global__ __launch_bounds__(256, 2) void gemm_bt(
    const bf16_t* __restrict__ A, const bf16_t* __restrict__ Bt,
    const float* __restrict__ bias, void* __restrict__ outp,
    int M, int N, int K) {
  __shared__ __align__(16) bf16_t As[128 * 64];
  __shared__ __align__(16) bf16_t Bs[128 * 64];
  const int tid = threadIdx.x;
  const int lane = tid & 63, wv = tid >> 6;
  const int quad = lane >> 4, l16 = lane & 15;
  // bijective XCD swizzle (nwg % 8 == 0 for all our launches)
  int nwg = gridDim.x * gridDim.y;
  int bid = blockIdx.y * gridDim.x + blockIdx.x;
  if (!(nwg & 7)) { int cpx = nwg >> 3; bid = (bid & 7) * cpx + (bid >> 3); }
  const int m_base = (bid / gridDim.x) * 128, n_base = (bid % gridDim.x) * 128;
  const int wm = wv & 1, wn = wv >> 1;
  f32x4 acc[4][4] = {};

  for (int k0 = 0; k0 < K; k0 += 64) {
#pragma unroll
    for (int c = 0; c < 4; c++) {
      int p = c * 256 + tid;                 // 1024 chunks: 128 rows x 8 chunks of 8 bf16
      int row = p >> 3;
      int gc = (p & 7) ^ (row & 7);          // XOR swizzle
      async_copy16(&A[(size_t)(m_base + row) * K + k0 + gc * 8], &As[(size_t)p * 8]);
      async_copy16(&Bt[(size_t)(n_base + row) * K + k0 + gc * 8], &Bs[(size_t)p * 8]);
    }
    __syncthreads();
#pragma unroll
    for (int ks = 0; ks < 2; ks++) {
      bf16x8 af[4], bfr[4];
#pragma unroll
      for (int mi = 0; mi < 4; mi++) {
        int r = wm * 64 + mi * 16 + l16;
        int c = (ks * 4 + quad) ^ (r & 7);
        af[mi] = *(const bf16x8*)&As[(size_t)(r * 8 + c) * 8];
      }
#pragma unroll
      for (int ni = 0; ni < 4; ni++) {
        int r = wn * 64 + ni * 16 + l16;
        int c = (ks * 4 + quad) ^ (r & 7);
        bfr[ni] = *(const bf16x8*)&Bs[(size_t)(r * 8 + c) * 8];
      }
#pragma unroll
      for (int mi = 0; mi < 4; mi++)
#pragma unroll
        for (int ni = 0; ni < 4; ni++)
          acc[mi][ni] = mfma16(af[mi], bfr[ni], acc[mi][ni]);
    }
    __syncthreads();
  }

#pragma unroll
  for (int mi = 0; mi < 4; mi++) {
    int m = m_base + wm * 64 + mi * 16 + quad * 4;
#pragma unroll
    for (int ni = 0; ni < 4; ni++) {
      int n = n_base + wn * 64 + ni * 16 + l16;
      float bv = bias[n];
#pragma unroll
      for (int r2 = 0; r2 < 4; r2++) {
        float v = acc[mi][ni][r2] + bv;
        if (EPI == 2) v = gelu_tanh(v);
        if (EPI == 0) ((float*)outp)[(size_t)(m + r2) * N + n] = v;
        else          ((bf16_t*)outp)[(size_t)(m + r2) * N + n] = (bf16_t)v;
      }
    }
  }
}

// ---------- GEMM 256x256 tile, BK=64, 8-phase, A-read-ahead pipeline (v4) ----------
// Register budget lesson (R4): acc=128 (AGPR) + frags must stay <=64 VGPR or spill.
// v4: af0/af1 double-buffered (32), bfr single (32) = 64, same as v2.
// B(next tile) is read AFTER the last MFMA consuming B(cur) (ph4/ph8, SF-pinned);
// its drain deadline is the NEXT phase's lgkmcnt(4). All MFMA operands are >=1
// phase old => pre-MFMA waits are lgkmcnt(4) (own 4 reads stay in flight) or none.
// lgkm ledger (steady): ph8 leaves 12 (ldB 8 + ldA rg0 4); ph1 +4 -> 16, w(4)
// drains 12; ph2/ph3 4->8, w(4); ph3 tail lgkmcnt(0) (WAR: A-half restage ph4)
// drains rg3 under MFMA; ph4 no wait (ops drained), +12 after MFMA. Mirror ph5-8.
// vmcnt(4) at ph3 confirms tile O (events ph2,ph3 in flight = 4 ops); at ph7
// confirms F. WAR restage deadlines all met at the preceding barrier.
#define SF __builtin_amdgcn_sched_barrier(0)

template <int EPI>
__global__ __launch_bounds__(512, 2) void gemm256(
    const bf16_t* __restrict__ A, const bf16_t* __restrict__ Bt,
    const float* __restrict__ bias, void* __restrict__ outp,
    int M, int N, int K) {
  __shared__ __align__(16) bf16_t As[2][256 * 64];
  __shared__ __align__(16) bf16_t Bs[2][256 * 64];
  const int tid = threadIdx.x;
  const int lane = tid & 63, wid = tid >> 6;
  const int quad = lane >> 4, l16 = lane & 15, l7 = l16 & 7;
  const int wm = wid >> 2, wn = wid & 3;
  int nwg = gridDim.x * gridDim.y;
  int bid = blockIdx.y * gridDim.x + blockIdx.x;
  if (!(nwg & 7)) { int cpx = nwg >> 3; bid = (bid & 7) * cpx + (bid >> 3); }
  const int m_base = (bid / gridDim.x) * 256, n_base = (bid % gridDim.x) * 256;
  const int nit = K >> 7;   // 2 K-tiles per iteration

  f32x4 acc[8][4] = {};

  // per-thread LDS read bases; everything else is compile-time immediates
  const bf16_t* aB[2]; const bf16_t* bB[2];
#pragma unroll
  for (int ks = 0; ks < 2; ks++) {
    aB[ks] = &As[0][0] + (wm * 128 + l16) * 64 + (((ks * 4 + quad) ^ l7)) * 8;
    bB[ks] = &Bs[0][0] + (wn * 64 + l16) * 64 + (((ks * 4 + quad) ^ l7)) * 8;
  }
  auto ldA = [&](int buf, int rg, bf16x8 (&af)[2][2]) {
#pragma unroll
    for (int mi = 0; mi < 2; mi++)
#pragma unroll
      for (int ks = 0; ks < 2; ks++)
        af[mi][ks] = *(const bf16x8*)(aB[ks] + buf * 16384 + rg * 2048 + mi * 1024);
  };
  auto ldB = [&](int buf, bf16x8 (&bfr)[4][2]) {
#pragma unroll
    for (int cf = 0; cf < 4; cf++)
#pragma unroll
      for (int ks = 0; ks < 2; ks++)
        bfr[cf][ks] = *(const bf16x8*)(bB[ks] + buf * 16384 + cf * 1024);
  };
  auto mm = [&](int rg, bf16x8 (&a)[2][2], bf16x8 (&b)[4][2]) {
#pragma unroll
    for (int ks = 0; ks < 2; ks++)
#pragma unroll
      for (int mi = 0; mi < 2; mi++)
#pragma unroll
        for (int cf = 0; cf < 4; cf++)
          acc[rg * 2 + mi][cf] = mfma16(a[mi][ks], b[cf][ks], acc[rg * 2 + mi][cf]);
  };

  // per-thread global stage streams, +128 B per stage event (K-tile order).
  // Streams run <=2 events past nkt (tail garbage staged, never read; sources
  // are followed by other live workspace buffers).
  const int rr = tid >> 3;
  const int cb = ((tid & 7) ^ (rr & 7)) * 16;
  const char* pa00 = (const char*)A + 2 * ((size_t)(m_base + 0 + rr) * K) + cb;
  const char* pa01 = (const char*)A + 2 * ((size_t)(m_base + 64 + rr) * K) + cb;
  const char* pa10 = (const char*)A + 2 * ((size_t)(m_base + 128 + rr) * K) + cb;
  const char* pa11 = (const char*)A + 2 * ((size_t)(m_base + 192 + rr) * K) + cb;
  const char* pb00 = (const char*)Bt + 2 * ((size_t)(n_base + 0 + rr) * K) + cb;
  const char* pb01 = (const char*)Bt + 2 * ((size_t)(n_base + 64 + rr) * K) + cb;
  const char* pb10 = (const char*)Bt + 2 * ((size_t)(n_base + 128 + rr) * K) + cb;
  const char* pb11 = (const char*)Bt + 2 * ((size_t)(n_base + 192 + rr) * K) + cb;
  bf16_t* dA0 = &As[0][0] + tid * 8;
  bf16_t* dB0 = &Bs[0][0] + tid * 8;
  auto stage = [&](const char*& p0, const char*& p1, bf16_t* d0) {
    async_copy16(p0, d0);
    async_copy16(p1, d0 + 4096);
    p0 += 128; p1 += 128;
  };

  // ---- prologue: E (kt0) fully + O (kt1) {Bh0,Bh1,Ah0}; vmcnt(6) confirms E ----
  stage(pb00, pb01, dB0);
  stage(pb10, pb11, dB0 + 8192);
  stage(pa00, pa01, dA0);
  stage(pa10, pa11, dA0 + 8192);
  stage(pb00, pb01, dB0 + 16384);
  stage(pb10, pb11, dB0 + 16384 + 8192);
  stage(pa00, pa01, dA0 + 16384);
  asm volatile("s_waitcnt vmcnt(6)" ::: "memory");
  SF; __builtin_amdgcn_s_barrier(); SF;

  bf16x8 af0[2][2], af1[2][2], bfr[4][2];
  ldB(0, bfr); ldA(0, 0, af0);   // 12 reads in flight entering ph1

  for (int it = 0; it < nit; ++it) {
    // ph1: MM rg0(E)[af0,bfr] | read rg1->af1 | stage O.Ah1
    ldA(0, 1, af1);
    stage(pa10, pa11, dA0 + 16384 + 8192);
    SF; asm volatile("s_waitcnt lgkmcnt(4)" ::: "memory"); SF;
    __builtin_amdgcn_s_setprio(1); mm(0, af0, bfr); __builtin_amdgcn_s_setprio(0);
    SF; __builtin_amdgcn_s_barrier(); SF;
    // ph2: MM rg1[af1,bfr] | read rg2->af0 | stage F.Bh0
    ldA(0, 2, af0);
    stage(pb00, pb01, dB0);
    SF; asm volatile("s_waitcnt lgkmcnt(4)" ::: "memory"); SF;
    __builtin_amdgcn_s_setprio(1); mm(1, af1, bfr); __builtin_amdgcn_s_setprio(0);
    SF; __builtin_amdgcn_s_barrier(); SF;
    // ph3: MM rg2[af0,bfr] | read rg3->af1 | stage F.Bh1 | tail: vmcnt(4)+lgkm(0)
    ldA(0, 3, af1);
    stage(pb10, pb11, dB0 + 8192);
    SF; asm volatile("s_waitcnt lgkmcnt(4)" ::: "memory"); SF;
    __builtin_amdgcn_s_setprio(1); mm(2, af0, bfr); __builtin_amdgcn_s_setprio(0);
    SF; asm volatile("s_waitcnt vmcnt(4) lgkmcnt(0)" ::: "memory");
    __builtin_amdgcn_s_barrier(); SF;
    // ph4: MM rg3[af1,bfr] | read A(O,rg0)->af0 | stage F.Ah0 | then ldB(O)->bfr
    ldA(1, 0, af0);
    stage(pa00, pa01, dA0);
    SF;
    __builtin_amdgcn_s_setprio(1); mm(3, af1, bfr); __builtin_amdgcn_s_setprio(0);
    SF;
    ldB(1, bfr);
    SF; __builtin_amdgcn_s_barrier(); SF;
    // ph5: MM rg0(O)[af0,bfr] | read rg1->af1 | stage F.Ah1
    ldA(1, 1, af1);
    stage(pa10, pa11, dA0 + 8192);
    SF; asm volatile("s_waitcnt lgkmcnt(4)" ::: "memory"); SF;
    __builtin_amdgcn_s_setprio(1); mm(0, af0, bfr); __builtin_amdgcn_s_setprio(0);
    SF; __builtin_amdgcn_s_barrier(); SF;
    // ph6: MM rg1[af1,bfr] | read rg2->af0 | stage G.Bh0
    ldA(1, 2, af0);
    stage(pb00, pb01, dB0 + 16384);
    SF; asm volatile("s_waitcnt lgkmcnt(4)" ::: "memory"); SF;
    __builtin_amdgcn_s_setprio(1); mm(1, af1, bfr); __builtin_amdgcn_s_setprio(0);
    SF; __builtin_amdgcn_s_barrier(); SF;
    // ph7: MM rg2[af0,bfr] | read rg3->af1 | stage G.Bh1 | tail: vmcnt(4)+lgkm(0)
    ldA(1, 3, af1);
    stage(pb10, pb11, dB0 + 16384 + 8192);
    SF; asm volatile("s_waitcnt lgkmcnt(4)" ::: "memory"); SF;
    __builtin_amdgcn_s_setprio(1); mm(2, af0, bfr); __builtin_amdgcn_s_setprio(0);
    SF; asm volatile("s_waitcnt vmcnt(4) lgkmcnt(0)" ::: "memory");
    __builtin_amdgcn_s_barrier(); SF;
    // ph8: MM rg3[af1,bfr] | read A(F,rg0)->af0 | stage G.Ah0 | then ldB(F)->bfr
    ldA(0, 0, af0);
    stage(pa00, pa01, dA0 + 16384);
    SF;
    __builtin_amdgcn_s_setprio(1); mm(3, af1, bfr); __builtin_amdgcn_s_setprio(0);
    SF;
    ldB(0, bfr);
    SF; __builtin_amdgcn_s_barrier(); SF;
  }
  asm volatile("s_waitcnt vmcnt(0) lgkmcnt(0)" ::: "memory");  // drain tail prefetches

#pragma unroll
  for (int rf = 0; rf < 8; rf++) {
    int m = m_base + wm * 128 + rf * 16 + quad * 4;
#pragma unroll
    for (int cf = 0; cf < 4; cf++) {
      int n = n_base + wn * 64 + cf * 16 + l16;
      float bv = bias[n];
#pragma unroll
      for (int r2 = 0; r2 < 4; r2++) {
        float v = acc[rf][cf][r2] + bv;
        if (EPI == 2) v = gelu_tanh(v);
        if (EPI == 0) ((float*)outp)[(size_t)(m + r2) * N + n] = v;
        else          ((bf16_t*)outp)[(size_t)(m + r2) * N + n] = (bf16_t)v;
      }
    }
  }
}

// ---------- GEMM 64x128 tile for small-K tail GEMMs ----------
template <int EPI>
__global__ __launch_bounds__(256, 2) void gemm64(
    const bf16_t* __restrict__ A, const bf16_t* __restrict__ Bt,
    const float* __restrict__ bias, void* __restrict__ outp,
    int M, int N, int K) {
  __shared__ __align__(16) bf16_t As[64 * 32];
  __shared__ __align__(16) bf16_t Bs[128 * 32];
  const int tid = threadIdx.x;
  const int lane = tid & 63, wv = tid >> 6;
  const int quad = lane >> 4, l16 = lane & 15;
  const int m_base = blockIdx.y * 64, n_base = blockIdx.x * 128;
  const int wm = wv & 1, wn = wv >> 1;
  f32x4 acc[2][4] = {};

  for (int k0 = 0; k0 < K; k0 += 32) {
    {
      int p = tid;                           // A: 64 rows x 4 chunks = 256
      int row = p >> 2;
      int kc = (p & 3) ^ ((row >> 1) & 3);
      async_copy16(&A[(size_t)(m_base + row) * K + k0 + kc * 8], &As[(size_t)p * 8]);
    }
#pragma unroll
    for (int c = 0; c < 2; c++) {
      int p = c * 256 + tid;                 // B: 128 rows x 4 chunks = 512
      int row = p >> 2;
      int kc = (p & 3) ^ ((row >> 1) & 3);
      async_copy16(&Bt[(size_t)(n_base + row) * K + k0 + kc * 8], &Bs[(size_t)p * 8]);
    }
    __syncthreads();
    bf16x8 af[2], bfr[4];
#pragma unroll
    for (int mi = 0; mi < 2; mi++) {
      int r = wm * 32 + mi * 16 + l16;
      int kc = quad ^ ((r >> 1) & 3);
      af[mi] = *(const bf16x8*)&As[(size_t)(r * 4 + kc) * 8];
    }
#pragma unroll
    for (int ni = 0; ni < 4; ni++) {
      int r = wn * 64 + ni * 16 + l16;
      int kc = quad ^ ((r >> 1) & 3);
      bfr[ni] = *(const bf16x8*)&Bs[(size_t)(r * 4 + kc) * 8];
    }
#pragma unroll
    for (int mi = 0; mi < 2; mi++)
#pragma unroll
      for (int ni = 0; ni < 4; ni++)
        acc[mi][ni] = mfma16(af[mi], bfr[ni], acc[mi][ni]);
    __syncthreads();
  }

#pragma unroll
  for (int mi = 0; mi < 2; mi++) {
    int m = m_base + wm * 32 + mi * 16 + quad * 4;
#pragma unroll
    for (int ni = 0; ni < 4; ni++) {
      int n = n_base + wn * 64 + ni * 16 + l16;
      float bv = bias[n];
#pragma unroll
      for (int r2 = 0; r2 < 4; r2++) {
        float v = acc[mi][ni][r2] + bv;
        if (EPI == 2) v = gelu_tanh(v);
        if (EPI == 0) ((float*)outp)[(size_t)(m + r2) * N + n] = v;
        else          ((bf16_t*)outp)[(size_t)(m + r2) * N + n] = (bf16_t)v;
      }
    }
  }
}

// ---------- fused dual-score attention, m97-style block-cooperative structure ----------
__global__ __launch_bounds__(256, 2) void attn_kernel(
    const bf16_t* __restrict__ qc, const bf16_t* __restrict__ qv,
    const bf16_t* __restrict__ kcb, const bf16_t* __restrict__ vkb,
    const bf16_t* __restrict__ vt, const float* __restrict__ lamp,
    bf16_t* __restrict__ vout) {
  const int b = blockIdx.z, h = blockIdx.y;
  const int tid = threadIdx.x;
  const int lane = tid & 63, wv = tid >> 6;
  const int quad = lane >> 4, l16 = lane & 15;
  const int qrow0 = blockIdx.x * 128 + wv * 32;
  const float SCL = 0.125f * 1.4426950408889634f;  // 1/sqrt(64) * log2(e)
  const float C1 = SCL, C2 = lamp[0] * SCL;

  __shared__ __align__(16) bf16_t kcS[64 * 64];
  __shared__ __align__(16) bf16_t kvS[64 * 64];
  __shared__ __align__(16) bf16_t vtS[64 * 64];
  __shared__ __align__(16) bf16_t sP[4][32 * 64];
  bf16_t* sPw = sP[wv];

  // Q fragments: A[m=q (l16)][k=d (ks*32+quad*8+j)]
  bf16x8 qcf[2][2], qvf[2][2];
#pragma unroll
  for (int mt = 0; mt < 2; mt++)
#pragma unroll
    for (int ks = 0; ks < 2; ks++) {
      size_t o = ((size_t)b * 4096 + qrow0 + mt * 16 + l16) * 512 + h * 64 + ks * 32 + quad * 8;
      qcf[mt][ks] = *(const bf16x8*)&qc[o];
      qvf[mt][ks] = *(const bf16x8*)&qv[o];
    }

  f32x4 O[2][4] = {};
  float ls[2][4] = {};

  for (int kb = 0; kb < 16; kb++) {
    // ---- stage kc/kv/vt 64x64 tiles (8 KB each): source-side XOR swizzle ----
#pragma unroll
    for (int i = 0; i < 2; i++) {
      int p = i * 256 + tid;            // 512 chunks of 16B per tile
      int row = p >> 3;                 // key row (kc/kv) or d row (vt)
      int gc = (p & 7) ^ (row & 7);     // global chunk for this LDS slot
      async_copy16(&kcb[((size_t)b * 1024 + kb * 64 + row) * 512 + h * 64 + gc * 8],
                   &kcS[(size_t)p * 8]);
      async_copy16(&vkb[((size_t)b * 1024 + kb * 64 + row) * 1024 + 512 + h * 64 + gc * 8],
                   &kvS[(size_t)p * 8]);
      async_copy16(&vt[((size_t)((b * 8 + h) * 64) + row) * 1024 + kb * 64 + gc * 8],
                   &vtS[(size_t)p * 8]);
    }
    __syncthreads();

    // ---- QK^T + exp -> per-wave P ----
#pragma unroll
    for (int nt = 0; nt < 4; nt++) {
      int krow = nt * 16 + l16;
      int kb8 = krow & 7;
      bf16x8 kc0 = *(const bf16x8*)&kcS[(size_t)(krow * 8 + (quad ^ kb8)) * 8];
      bf16x8 kc1 = *(const bf16x8*)&kcS[(size_t)(krow * 8 + ((4 + quad) ^ kb8)) * 8];
      bf16x8 kv0 = *(const bf16x8*)&kvS[(size_t)(krow * 8 + (quad ^ kb8)) * 8];
      bf16x8 kv1 = *(const bf16x8*)&kvS[(size_t)(krow * 8 + ((4 + quad) ^ kb8)) * 8];
#pragma unroll
      for (int mt = 0; mt < 2; mt++) {
        f32x4 sc = {};
        sc = mfma16(qcf[mt][0], kc0, sc);
        sc = mfma16(qcf[mt][1], kc1, sc);
        f32x4 sv = {};
        sv = mfma16(qvf[mt][0], kv0, sv);
        sv = mfma16(qvf[mt][1], kv1, sv);
#pragma unroll
        for (int r = 0; r < 4; r++) {
          float p = exp2f(sc[r] * C1 + sv[r] * C2);
          ls[mt][r] += p;
          int prow = mt * 16 + quad * 4 + r;
          int col = nt * 16 + l16;
          sPw[prow * 64 + (((col >> 3) ^ (prow & 7)) * 8) + (col & 7)] = (bf16_t)p;
        }
      }
    }
    // RAW: this wave's P writes must land before its reads (per-wave buffer)
    asm volatile("s_waitcnt lgkmcnt(0)" ::: "memory");

    // ---- PV: O[mt] += P[mt] @ V ----
#pragma unroll
    for (int ks2 = 0; ks2 < 2; ks2++) {
      bf16x8 pa[2];
#pragma unroll
      for (int mt = 0; mt < 2; mt++) {
        int prow = mt * 16 + l16;
        pa[mt] = *(const bf16x8*)&sPw[(size_t)(prow * 8 + ((ks2 * 4 + quad) ^ (prow & 7))) * 8];
      }
#pragma unroll
      for (int ntd = 0; ntd < 4; ntd++) {
        int drow = ntd * 16 + l16;
        bf16x8 vb = *(const bf16x8*)&vtS[(size_t)(drow * 8 + ((ks2 * 4 + quad) ^ (drow & 7))) * 8];
        O[0][ntd] = mfma16(pa[0], vb, O[0][ntd]);
        O[1][ntd] = mfma16(pa[1], vb, O[1][ntd]);
      }
    }
    __syncthreads();  // protect kc/kv/vt tiles before next stage (also WAR for sPw)
  }

  // ---- epilogue: denominator + write ----
#pragma unroll
  for (int mt = 0; mt < 2; mt++) {
    float inv[4];
#pragma unroll
    for (int r = 0; r < 4; r++) {
      float v = ls[mt][r];
      v += __shfl_xor(v, 1);
      v += __shfl_xor(v, 2);
      v += __shfl_xor(v, 4);
      v += __shfl_xor(v, 8);
      inv[r] = 1.f / v;
    }
#pragma unroll
    for (int ntd = 0; ntd < 4; ntd++)
#pragma unroll
      for (int r = 0; r < 4; r++) {
        size_t o = ((size_t)b * 4096 + qrow0 + mt * 16 + quad * 4 + r) * 512 + h * 64 + ntd * 16 + l16;
        vout[o] = (bf16_t)(O[mt][ntd][r] * inv[r]);
      }
  }
}

extern "C" void kernel_launch(void* const* d_in, const int* in_sizes, int n_in,
                              void* d_out, int out_size, void* d_ws, size_t ws_size,
                              hipStream_t stream) {
  (void)in_sizes; (void)n_in; (void)out_size; (void)ws_size;
  const float* coords = (const float*)d_in[0];
  const float* values = (const float*)d_in[1];
  const float* Lv     = (const float*)d_in[2];
  const float* Lc     = (const float*)d_in[3];
  const float* lam    = (const float*)d_in[4];
  const float* lvn_g  = (const float*)d_in[5];
  const float* lvn_b  = (const float*)d_in[6];
  const float* lcn_g  = (const float*)d_in[7];
  const float* lcn_b  = (const float*)d_in[8];
  const float* ck_w = (const float*)d_in[9];  const float* ck_b = (const float*)d_in[10]; const float* ck_g = (const float*)d_in[11];
  const float* cq_w = (const float*)d_in[12]; const float* cq_b = (const float*)d_in[13]; const float* cq_g = (const float*)d_in[14];
  const float* vq_w = (const float*)d_in[15]; const float* vq_b = (const float*)d_in[16]; const float* vq_g = (const float*)d_in[17];
  const float* vk_w = (const float*)d_in[18]; const float* vk_b = (const float*)d_in[19];
  const float* op_w = (const float*)d_in[20]; const float* op_b = (const float*)d_in[21];
  const float* oln_g = (const float*)d_in[22]; const float* oln_b = (const float*)d_in[23];
  const float* m1_w = (const float*)d_in[24]; const float* m1_b = (const float*)d_in[25];
  const float* m2_w = (const float*)d_in[26]; const float* m2_b = (const float*)d_in[27];
  const float* m3_w = (const float*)d_in[28]; const float* m3_b = (const float*)d_in[29];

  char* ws = (char*)d_ws;
  size_t off = 0;
  auto alloc = [&](size_t bytes) { void* p = ws + off; off += (bytes + 255) & ~(size_t)255; return p; };

  // persistent region
  bf16_t* wt_m1 = (bf16_t*)alloc((size_t)512 * 2048 * 2);
  bf16_t* wt_m2 = (bf16_t*)alloc((size_t)2048 * 2048 * 2);
  bf16_t* wt_m3 = (bf16_t*)alloc((size_t)2048 * 512 * 2);
  bf16_t* scr0  = (bf16_t*)alloc((size_t)16384 * 512 * 4);   // bf16 used, f32-sized slot kept
  bf16_t* qv_bf = (bf16_t*)alloc((size_t)16384 * 512 * 2);
  bf16_t* qc_bf = (bf16_t*)alloc((size_t)16384 * 512 * 2);
  bf16_t* voutb = (bf16_t*)alloc((size_t)16384 * 512 * 2);
  bf16_t* h0    = (bf16_t*)alloc((size_t)16384 * 512 * 2);
  bf16_t* h1    = (bf16_t*)alloc((size_t)16384 * 2048 * 2);
  bf16_t* h2    = (bf16_t*)alloc((size_t)16384 * 2048 * 2);

  // overlay region: everything here is dead before h1 is written (m1 GEMM)
  size_t ov = (size_t)((char*)h1 - ws);
  auto oalloc = [&](size_t bytes) { void* p = ws + ov; ov += (bytes + 255) & ~(size_t)255; return p; };
  bf16_t* wt_vk = (bf16_t*)oalloc((size_t)1024 * 512 * 2);
  bf16_t* wt_ck = (bf16_t*)oalloc((size_t)512 * 128 * 2);
  bf16_t* wt_cq = (bf16_t*)oalloc((size_t)512 * 128 * 2);
  bf16_t* wt_vq = (bf16_t*)oalloc((size_t)512 * 512 * 2);
  bf16_t* wt_op = (bf16_t*)oalloc((size_t)512 * 512 * 2);
  bf16_t* lv_ln = (bf16_t*)oalloc((size_t)4096 * 512 * 2);
  bf16_t* lc_ln = (bf16_t*)oalloc((size_t)4096 * 128 * 2);
  bf16_t* vkob  = (bf16_t*)oalloc((size_t)4096 * 1024 * 2);
  bf16_t* kc_b  = (bf16_t*)oalloc((size_t)4096 * 512 * 2);
  bf16_t* kc_bf = (bf16_t*)oalloc((size_t)4096 * 512 * 2);
  bf16_t* val_bf= (bf16_t*)oalloc((size_t)16384 * 512 * 2);
  bf16_t* crd_bf= (bf16_t*)oalloc((size_t)16384 * 128 * 2);
  bf16_t* vt    = (bf16_t*)oalloc((size_t)4 * 512 * 1024 * 2);

  // ---- single batched transpose launch for all 8 weights ----
  TransBatch tb8;
  const float* srcs[8] = {vk_w, ck_w, cq_w, vq_w, op_w, m1_w, m2_w, m3_w};
  bf16_t* dsts[8] = {wt_vk, wt_ck, wt_cq, wt_vq, wt_op, wt_m1, wt_m2, wt_m3};
  int Ks[8] = {512, 128, 128, 512, 512, 512, 2048, 2048};
  int Ns[8] = {1024, 512, 512, 512, 512, 2048, 2048, 512};
  int cum = 0;
  for (int i = 0; i < 8; i++) {
    tb8.src[i] = srcs[i]; tb8.dst[i] = dsts[i];
    tb8.K[i] = Ks[i]; tb8.N[i] = Ns[i];
    tb8.bx[i] = Ns[i] / 32;
    tb8.base[i] = cum;
    cum += (Ns[i] / 32) * (Ks[i] / 32);
  }
  transpose_batch_kernel<<<cum, dim3(32, 8), 0, stream>>>(tb8);

  cvt2_bf16_kernel<<<(16384 * 512 / 4 + 16384 * 128 / 4 + 255) / 256, 256, 0, stream>>>(
      values, val_bf, 16384 * 512 / 4, coords, crd_bf, 16384 * 128 / 4);

  rownorm_kernel<512, false, float><<<1024, 256, 0, stream>>>(Lv, lvn_g, lvn_b, lv_ln);
  rownorm_kernel<128, false, float><<<1024, 256, 0, stream>>>(Lc, lcn_g, lcn_b, lc_ln);

  gemm_bt<1><<<dim3(8, 32), 256, 0, stream>>>(lv_ln, wt_vk, vk_b, vkob, 4096, 1024, 512);
  gemm64<1><<<dim3(4, 64), 256, 0, stream>>>(lc_ln, wt_ck, ck_b, kc_b, 4096, 512, 128);
  rownorm_kernel<512, true, bf16_t><<<1024, 256, 0, stream>>>(kc_b, ck_g, nullptr, kc_bf);

  gemm_bt<1><<<dim3(4, 128), 256, 0, stream>>>(val_bf, wt_vq, vq_b, scr0, 16384, 512, 512);
  rownorm_kernel<512, true, bf16_t><<<4096, 256, 0, stream>>>(scr0, vq_g, nullptr, qv_bf);
  gemm64<1><<<dim3(4, 256), 256, 0, stream>>>(crd_bf, wt_cq, cq_b, scr0, 16384, 512, 128);
  rownorm_kernel<512, true, bf16_t><<<4096, 256, 0, stream>>>(scr0, cq_g, nullptr, qc_bf);

  transpose_v_kernel<<<dim3(16, 32, 4), dim3(32, 8), 0, stream>>>(vkob, vt);

  attn_kernel<<<dim3(32, 8, 4), 256, 0, stream>>>(qc_bf, qv_bf, kc_bf, vkob, vt, lam, voutb);

  gemm_bt<1><<<dim3(4, 128), 256, 0, stream>>>(voutb, wt_op, op_b, scr0, 16384, 512, 512);
  rownorm_kernel<512, false, bf16_t><<<4096, 256, 0, stream>>>(scr0, oln_g, oln_b, h0);

  gemm256<2><<<dim3(8, 64), 512, 0, stream>>>(h0, wt_m1, m1_b, h1, 16384, 2048, 512);
  gemm256<2><<<dim3(8, 64), 512, 0, stream>>>(h1, wt_m2, m2_b, h2, 16384, 2048, 2048);
  gemm_bt<0><<<dim3(4, 128), 256, 0, stream>>>(h2, wt_m3, m3_b, (float*)d_out, 16384, 512, 2048);
}